// Round 1
// baseline (306.225 us; speedup 1.0000x reference)
//
#include <hip/hip_runtime.h>
#include <hip/hip_bf16.h>

// Quanvolution classifier:
//   x (B,1,28,28) -> 2x2 patches (B,196,4) -> RY-encode 4 qubits ->
//   fixed variational unitary U (from vparams) -> <Z_w> feats (B,784) ->
//   logits = feats @ W^T + b -> log_softmax.
//
// Key algebra: variational circuit is data-independent => precompute U (16x16
// complex). Encoder state is a REAL product state s. Per patch: psi = U*s,
// probs = |psi|^2, e_w = sum_i sign_w(i) probs[i].
//
// Wire convention (torchquantum / reference): wire 0 = MSB of the 4-bit
// amplitude index; bit of wire w is (8 >> w).

#define NPATCH 196

// ---------------- kernel 1: build U from vparams -------------------------
__global__ void qc_build_unitary(const float* __restrict__ vp,
                                 float* __restrict__ Uout) {
  int j = threadIdx.x;
  if (j >= 16) return;
  float sr[16], si[16];
#pragma unroll
  for (int i = 0; i < 16; ++i) { sr[i] = 0.f; si[i] = 0.f; }
  sr[j] = 1.f;

  for (int l = 0; l < 3; ++l) {
#pragma unroll
    for (int w = 0; w < 4; ++w) {
      float thy = vp[l * 8 + (w % 8)];
      float thz = vp[l * 8 + ((w + 1) % 8)];
      float cy, sy, cz, sz;
      __sincosf(0.5f * thy, &sy, &cy);
      __sincosf(0.5f * thz, &sz, &cz);
      const int bit = 8 >> w;
      // RY(thy) on wire w: a0' = c a0 - s a1 ; a1' = s a0 + c a1
#pragma unroll
      for (int i = 0; i < 16; ++i) {
        if (!(i & bit)) {
          int i1 = i | bit;
          float a0r = sr[i], a0i = si[i], a1r = sr[i1], a1i = si[i1];
          sr[i]  = cy * a0r - sy * a1r;  si[i]  = cy * a0i - sy * a1i;
          sr[i1] = sy * a0r + cy * a1r;  si[i1] = sy * a0i + cy * a1i;
        }
      }
      // RZ(thz) on wire w: amp0 *= e^{-i thz/2}, amp1 *= e^{+i thz/2}
#pragma unroll
      for (int i = 0; i < 16; ++i) {
        float r = sr[i], m = si[i];
        if (i & bit) { sr[i] = r * cz - m * sz; si[i] = m * cz + r * sz; }
        else         { sr[i] = r * cz + m * sz; si[i] = m * cz - r * sz; }
      }
    }
    // CX ring: control w, target (w+1)%4 — swap target bit where control=1
#pragma unroll
    for (int w = 0; w < 4; ++w) {
      const int cbit = 8 >> w;
      const int tbit = 8 >> ((w + 1) & 3);
#pragma unroll
      for (int i = 0; i < 16; ++i) {
        if ((i & cbit) && !(i & tbit)) {
          int i1 = i | tbit;
          float tr = sr[i], ti = si[i];
          sr[i] = sr[i1]; si[i] = si[i1];
          sr[i1] = tr;    si[i1] = ti;
        }
      }
    }
  }
#pragma unroll
  for (int i = 0; i < 16; ++i) {
    Uout[i * 16 + j]       = sr[i];   // Ur, row-major
    Uout[256 + i * 16 + j] = si[i];   // Ui
  }
}

// ---------------- kernel 2: per-patch simulation -> feats ----------------
// One thread = 4 consecutive patches of one sample (amortizes LDS broadcast
// of U across 8 FMAs per load so we are VALU- not LDS-pipe-bound).
// grid covers B*49 quad-patches; B=4096 -> exactly 784 blocks x 256 threads.
__global__ __launch_bounds__(256) void qc_sim(const float* __restrict__ x,
                                              const float* __restrict__ U,
                                              float4* __restrict__ feats,
                                              int total) {
  __shared__ float sU[512];  // [0,256): Ur  [256,512): Ui
  int tid = threadIdx.x;
  sU[tid]       = U[tid];
  sU[tid + 256] = U[tid + 256];
  __syncthreads();

  int idx = blockIdx.x * 256 + tid;
  if (idx >= total) return;
  int b = idx / 49;
  int q = idx - b * 49;  // quad-patch index, patches 4q..4q+3
  const float* xb = x + (size_t)b * 784;

  float sv[4][16];
#pragma unroll
  for (int k = 0; k < 4; ++k) {
    int p = 4 * q + k;
    int pr = p / 14;
    int pc = p - pr * 14;
    float2 top = *(const float2*)(xb + (2 * pr) * 28 + 2 * pc);
    float2 bot = *(const float2*)(xb + (2 * pr + 1) * 28 + 2 * pc);
    float s0, c0, s1, c1, s2, c2, s3, c3;
    __sincosf(0.5f * top.x, &s0, &c0);
    __sincosf(0.5f * top.y, &s1, &c1);
    __sincosf(0.5f * bot.x, &s2, &c2);
    __sincosf(0.5f * bot.y, &s3, &c3);
    float p00 = c0 * c1, p01 = c0 * s1, p10 = s0 * c1, p11 = s0 * s1;
    float q00 = c2 * c3, q01 = c2 * s3, q10 = s2 * c3, q11 = s2 * s3;
    sv[k][0] = p00 * q00;  sv[k][1] = p00 * q01;  sv[k][2]  = p00 * q10;  sv[k][3]  = p00 * q11;
    sv[k][4] = p01 * q00;  sv[k][5] = p01 * q01;  sv[k][6]  = p01 * q10;  sv[k][7]  = p01 * q11;
    sv[k][8] = p10 * q00;  sv[k][9] = p10 * q01;  sv[k][10] = p10 * q10;  sv[k][11] = p10 * q11;
    sv[k][12] = p11 * q00; sv[k][13] = p11 * q01; sv[k][14] = p11 * q10;  sv[k][15] = p11 * q11;
  }

  float e[4][4];
#pragma unroll
  for (int k = 0; k < 4; ++k)
#pragma unroll
    for (int w = 0; w < 4; ++w) e[k][w] = 0.f;

#pragma unroll
  for (int i = 0; i < 16; ++i) {
    const float4* urp = (const float4*)&sU[i * 16];
    const float4* uip = (const float4*)&sU[256 + i * 16];
    float4 ur0 = urp[0], ur1 = urp[1], ur2 = urp[2], ur3 = urp[3];
    float4 ui0 = uip[0], ui1 = uip[1], ui2 = uip[2], ui3 = uip[3];
#pragma unroll
    for (int k = 0; k < 4; ++k) {
      const float* s = sv[k];
      float re = ur0.x * s[0] + ur0.y * s[1] + ur0.z * s[2] + ur0.w * s[3]
               + ur1.x * s[4] + ur1.y * s[5] + ur1.z * s[6] + ur1.w * s[7]
               + ur2.x * s[8] + ur2.y * s[9] + ur2.z * s[10] + ur2.w * s[11]
               + ur3.x * s[12] + ur3.y * s[13] + ur3.z * s[14] + ur3.w * s[15];
      float im = ui0.x * s[0] + ui0.y * s[1] + ui0.z * s[2] + ui0.w * s[3]
               + ui1.x * s[4] + ui1.y * s[5] + ui1.z * s[6] + ui1.w * s[7]
               + ui2.x * s[8] + ui2.y * s[9] + ui2.z * s[10] + ui2.w * s[11]
               + ui3.x * s[12] + ui3.y * s[13] + ui3.z * s[14] + ui3.w * s[15];
      float pb = re * re + im * im;
      e[k][0] += (i & 8) ? -pb : pb;
      e[k][1] += (i & 4) ? -pb : pb;
      e[k][2] += (i & 2) ? -pb : pb;
      e[k][3] += (i & 1) ? -pb : pb;
    }
  }

  float4* fb = feats + (size_t)b * NPATCH + 4 * q;
#pragma unroll
  for (int k = 0; k < 4; ++k)
    fb[k] = make_float4(e[k][0], e[k][1], e[k][2], e[k][3]);
}

// ---------------- kernel 3: head (feats @ W^T + b, log_softmax) ----------
// One wave (64 threads) per sample.
__global__ __launch_bounds__(64) void qc_head(const float4* __restrict__ feats,
                                              const float4* __restrict__ W4,
                                              const float* __restrict__ bias,
                                              float* __restrict__ out) {
  int b = blockIdx.x;
  int lane = threadIdx.x;
  float lg[10];
#pragma unroll
  for (int c = 0; c < 10; ++c) lg[c] = 0.f;

  const float4* fb = feats + (size_t)b * NPATCH;
#pragma unroll
  for (int k = 0; k < 4; ++k) {
    int t = lane + 64 * k;
    if (t < NPATCH) {
      float4 f = fb[t];
#pragma unroll
      for (int c = 0; c < 10; ++c) {
        float4 w = W4[c * NPATCH + t];
        lg[c] += f.x * w.x + f.y * w.y + f.z * w.z + f.w * w.w;
      }
    }
  }
  // 64-lane butterfly reduce for each of the 10 logits
#pragma unroll
  for (int off = 32; off >= 1; off >>= 1)
#pragma unroll
    for (int c = 0; c < 10; ++c)
      lg[c] += __shfl_xor(lg[c], off, 64);

  if (lane == 0) {
    float L[10], m = -1e30f;
#pragma unroll
    for (int c = 0; c < 10; ++c) { L[c] = lg[c] + bias[c]; m = fmaxf(m, L[c]); }
    float ssum = 0.f;
#pragma unroll
    for (int c = 0; c < 10; ++c) ssum += __expf(L[c] - m);
    float ls = m + __logf(ssum);
#pragma unroll
    for (int c = 0; c < 10; ++c) out[b * 10 + c] = L[c] - ls;
  }
}

extern "C" void kernel_launch(void* const* d_in, const int* in_sizes, int n_in,
                              void* d_out, int out_size, void* d_ws, size_t ws_size,
                              hipStream_t stream) {
  const float* x    = (const float*)d_in[0];  // (B,1,28,28)
  const float* vp   = (const float*)d_in[1];  // (3,8)
  const float* W    = (const float*)d_in[2];  // (10,784)
  const float* bias = (const float*)d_in[3];  // (10,)
  float* out = (float*)d_out;

  int B = in_sizes[0] / 784;

  float*  Uws   = (float*)d_ws;                        // 512 floats (2 KB)
  float4* feats = (float4*)((char*)d_ws + 2048);       // B*196 float4 (12.8 MB @ B=4096)

  qc_build_unitary<<<1, 64, 0, stream>>>(vp, Uws);

  int total = B * 49;  // quad-patches
  qc_sim<<<(total + 255) / 256, 256, 0, stream>>>(x, Uws, feats, total);

  qc_head<<<B, 64, 0, stream>>>(feats, (const float4*)W, bias, out);
}

// Round 2
// 97.832 us; speedup vs baseline: 3.1301x; 3.1301x over previous
//
#include <hip/hip_runtime.h>
#include <hip/hip_bf16.h>

// Quanvolution classifier, round 2.
//
// Algebra: variational circuit is data-independent => U (16x16 complex) fixed.
// Encoder state is a real product state s = p (x) q, p,q in R^4.
//   e_w = s^T M_w s,  M_w = Re(U^dag Z_w U)  (real symmetric 16x16)
// Fold pair symmetry:  e_w = sum_{a,b in 10} C_w[a][b] P_a Q_b
// where P_a = p_{j1}p_{j2} over unique pairs (j1<=j2), same for Q.
// => per patch: 4 sincos + ~24 mul + 440 FMA, C (400 floats) read at
// wave-uniform addresses -> scalar (SGPR) loads, no LDS, no spill.
//
// Wire convention (validated in round 1): wire 0 = MSB; i = 4*jp + jq,
// s[i] = p[jp]*q[jq], p = (c0c1, c0s1, s0c1, s0s1), q = (c2c3, c2s3, s2c3, s2s3).

#define NPATCH 196

// ---------------- kernel 1: vparams -> U -> M_w -> C (400 floats) --------
__global__ void qc_build_C(const float* __restrict__ vp,
                           float* __restrict__ Cout) {
  __shared__ float Ur[16][16];   // [i][j]
  __shared__ float Ui[16][16];
  __shared__ float M[4][16][16];
  int t = threadIdx.x;

  if (t < 16) {
    // evolve basis column t through the 3 variational layers
    float sr[16], si[16];
#pragma unroll
    for (int i = 0; i < 16; ++i) { sr[i] = 0.f; si[i] = 0.f; }
    sr[t] = 1.f;

    for (int l = 0; l < 3; ++l) {
#pragma unroll
      for (int w = 0; w < 4; ++w) {
        float thy = vp[l * 8 + (w % 8)];
        float thz = vp[l * 8 + ((w + 1) % 8)];
        float cy, sy, cz, sz;
        __sincosf(0.5f * thy, &sy, &cy);
        __sincosf(0.5f * thz, &sz, &cz);
        const int bit = 8 >> w;
        // RY
#pragma unroll
        for (int i = 0; i < 16; ++i) {
          if (!(i & bit)) {
            int i1 = i | bit;
            float a0r = sr[i], a0i = si[i], a1r = sr[i1], a1i = si[i1];
            sr[i]  = cy * a0r - sy * a1r;  si[i]  = cy * a0i - sy * a1i;
            sr[i1] = sy * a0r + cy * a1r;  si[i1] = sy * a0i + cy * a1i;
          }
        }
        // RZ: amp0 *= e^{-i thz/2}, amp1 *= e^{+i thz/2}
#pragma unroll
        for (int i = 0; i < 16; ++i) {
          float r = sr[i], m = si[i];
          if (i & bit) { sr[i] = r * cz - m * sz; si[i] = m * cz + r * sz; }
          else         { sr[i] = r * cz + m * sz; si[i] = m * cz - r * sz; }
        }
      }
      // CX ring
#pragma unroll
      for (int w = 0; w < 4; ++w) {
        const int cbit = 8 >> w;
        const int tbit = 8 >> ((w + 1) & 3);
#pragma unroll
        for (int i = 0; i < 16; ++i) {
          if ((i & cbit) && !(i & tbit)) {
            int i1 = i | tbit;
            float tr = sr[i], ti = si[i];
            sr[i] = sr[i1]; si[i] = si[i1];
            sr[i1] = tr;    si[i1] = ti;
          }
        }
      }
    }
#pragma unroll
    for (int i = 0; i < 16; ++i) { Ur[i][t] = sr[i]; Ui[i][t] = si[i]; }
  }
  __syncthreads();

  // M_w[r][c] = sum_i sgn_w(i) * (Ur[i][r]Ur[i][c] + Ui[i][r]Ui[i][c])
  for (int e = t; e < 1024; e += 64) {
    int w = e >> 8, r = (e >> 4) & 15, c = e & 15;
    float acc = 0.f;
#pragma unroll
    for (int i = 0; i < 16; ++i) {
      float sgn = ((i >> (3 - w)) & 1) ? -1.f : 1.f;
      acc += sgn * (Ur[i][r] * Ur[i][c] + Ui[i][r] * Ui[i][c]);
    }
    M[w][r][c] = acc;
  }
  __syncthreads();

  // C_w[a][b] = sum over distinct orderings of pair a (rows) x pair b (cols)
  const int pj1[10] = {0, 0, 0, 0, 1, 1, 1, 2, 2, 3};
  const int pj2[10] = {0, 1, 2, 3, 1, 2, 3, 2, 3, 3};
  for (int e = t; e < 400; e += 64) {
    int w = e / 100;
    int rem = e - w * 100;
    int a = rem / 10;
    int bq = rem - a * 10;
    int j1 = pj1[a], j2 = pj2[a], k1 = pj1[bq], k2 = pj2[bq];
    float v = M[w][4 * j1 + k1][4 * j2 + k2];
    if (k1 != k2) v += M[w][4 * j1 + k2][4 * j2 + k1];
    if (j1 != j2) {
      v += M[w][4 * j2 + k1][4 * j1 + k2];
      if (k1 != k2) v += M[w][4 * j2 + k2][4 * j1 + k1];
    }
    Cout[e] = v;
  }
}

// ---------------- kernel 2: per-patch quadratic form -> feats ------------
// One thread = one patch. C is read at wave-uniform addresses -> SGPRs.
__global__ __launch_bounds__(256) void qc_sim(const float* __restrict__ x,
                                              const float* __restrict__ C,
                                              float4* __restrict__ feats,
                                              int total) {
  int idx = blockIdx.x * 256 + threadIdx.x;
  if (idx >= total) return;
  int b = idx / 196;
  int p = idx - b * 196;
  int pr = p / 14;
  int pc = p - pr * 14;
  const float* xb = x + (size_t)b * 784;

  float2 top = *(const float2*)(xb + (2 * pr) * 28 + 2 * pc);
  float2 bot = *(const float2*)(xb + (2 * pr + 1) * 28 + 2 * pc);
  float s0, c0, s1, c1, s2, c2, s3, c3;
  __sincosf(0.5f * top.x, &s0, &c0);
  __sincosf(0.5f * top.y, &s1, &c1);
  __sincosf(0.5f * bot.x, &s2, &c2);
  __sincosf(0.5f * bot.y, &s3, &c3);

  float p0 = c0 * c1, p1 = c0 * s1, p2 = s0 * c1, p3 = s0 * s1;
  float q0 = c2 * c3, q1 = c2 * s3, q2 = s2 * c3, q3 = s2 * s3;

  float P[10] = {p0 * p0, p0 * p1, p0 * p2, p0 * p3, p1 * p1,
                 p1 * p2, p1 * p3, p2 * p2, p2 * p3, p3 * p3};
  float Q[10] = {q0 * q0, q0 * q1, q0 * q2, q0 * q3, q1 * q1,
                 q1 * q2, q1 * q3, q2 * q2, q2 * q3, q3 * q3};

  float e[4];
#pragma unroll
  for (int w = 0; w < 4; ++w) {
    float acc = 0.f;
#pragma unroll
    for (int a = 0; a < 10; ++a) {
      const float* row = C + (w * 10 + a) * 10;
      float tt = row[0] * Q[0] + row[1] * Q[1] + row[2] * Q[2] +
                 row[3] * Q[3] + row[4] * Q[4] + row[5] * Q[5] +
                 row[6] * Q[6] + row[7] * Q[7] + row[8] * Q[8] +
                 row[9] * Q[9];
      acc += P[a] * tt;
    }
    e[w] = acc;
  }
  feats[idx] = make_float4(e[0], e[1], e[2], e[3]);
}

// ---------------- kernel 3: head (feats @ W^T + b, log_softmax) ----------
__global__ __launch_bounds__(64) void qc_head(const float4* __restrict__ feats,
                                              const float4* __restrict__ W4,
                                              const float* __restrict__ bias,
                                              float* __restrict__ out) {
  int b = blockIdx.x;
  int lane = threadIdx.x;
  float lg[10];
#pragma unroll
  for (int c = 0; c < 10; ++c) lg[c] = 0.f;

  const float4* fb = feats + (size_t)b * NPATCH;
#pragma unroll
  for (int k = 0; k < 4; ++k) {
    int t = lane + 64 * k;
    if (t < NPATCH) {
      float4 f = fb[t];
#pragma unroll
      for (int c = 0; c < 10; ++c) {
        float4 w = W4[c * NPATCH + t];
        lg[c] += f.x * w.x + f.y * w.y + f.z * w.z + f.w * w.w;
      }
    }
  }
#pragma unroll
  for (int off = 32; off >= 1; off >>= 1)
#pragma unroll
    for (int c = 0; c < 10; ++c)
      lg[c] += __shfl_xor(lg[c], off, 64);

  if (lane == 0) {
    float L[10], m = -1e30f;
#pragma unroll
    for (int c = 0; c < 10; ++c) { L[c] = lg[c] + bias[c]; m = fmaxf(m, L[c]); }
    float ssum = 0.f;
#pragma unroll
    for (int c = 0; c < 10; ++c) ssum += __expf(L[c] - m);
    float ls = m + __logf(ssum);
#pragma unroll
    for (int c = 0; c < 10; ++c) out[b * 10 + c] = L[c] - ls;
  }
}

extern "C" void kernel_launch(void* const* d_in, const int* in_sizes, int n_in,
                              void* d_out, int out_size, void* d_ws, size_t ws_size,
                              hipStream_t stream) {
  const float* x    = (const float*)d_in[0];  // (B,1,28,28)
  const float* vp   = (const float*)d_in[1];  // (3,8)
  const float* W    = (const float*)d_in[2];  // (10,784)
  const float* bias = (const float*)d_in[3];  // (10,)
  float* out = (float*)d_out;

  int B = in_sizes[0] / 784;

  float*  Cws   = (float*)d_ws;                   // 400 floats (1.6 KB)
  float4* feats = (float4*)((char*)d_ws + 2048);  // B*196 float4 (12.8 MB)

  qc_build_C<<<1, 64, 0, stream>>>(vp, Cws);

  int total = B * NPATCH;
  qc_sim<<<(total + 255) / 256, 256, 0, stream>>>(x, Cws, feats, total);

  qc_head<<<B, 64, 0, stream>>>(feats, (const float4*)W, bias, out);
}